// Round 21
// baseline (96.533 us; speedup 1.0000x reference)
//
#include <hip/hip_runtime.h>
#include <hip/hip_bf16.h>

#define HH 1024
#define LL 2048
#define BB 8
#define NN2 32     // complex modes
#define CT 128     // chunk size
#define NCH 16     // LL / CT

typedef short bf16x8 __attribute__((ext_vector_type(8)));
typedef float f32x4  __attribute__((ext_vector_type(4)));

static __device__ __forceinline__ unsigned short bfbits(float x) {
    __hip_bfloat16 h = __float2bfloat16(x);
    return *(unsigned short*)&h;
}
static __device__ __forceinline__ float f_from_bits(unsigned short b) {
    __hip_bfloat16 h; *(unsigned short*)&h = b; return __bfloat162float(h);
}
// exp(dA * p), native ops, explicit range reduction.
static __device__ __forceinline__ float2 cexp_n(float2 dA, float p) {
    float mag = __expf(dA.x * p);
    float rev = dA.y * p * 0.15915494309f;
    rev -= floorf(rev);
    float ang = rev * 6.28318530718f;
    return make_float2(mag * __cosf(ang), mag * __sinf(ang));
}
static __device__ __forceinline__ float gelu_f(float y) {
    float z = 0.7978845608f * (y + 0.044715f * y * y * y);
    float e = __expf(2.0f * z);
    return 0.5f * y * (1.0f + (1.0f - 2.0f / (e + 1.0f)));
}

#define SWZ(off, row) ((off) ^ (((row) & 7) << 4))

// ---------------------------------------------------------------------------
// Kernel 0: per-h tables -> global, PRE-SWIZZLED. (R20 verbatim)
// misc = 384 floats: kt[128] | Cn[64] | A128[64] | dtA[64] | pad[64]
// ---------------------------------------------------------------------------
__global__ __launch_bounds__(256) void aux_tables(
    const float* __restrict__ log_dt, const float* __restrict__ log_w_real,
    const float* __restrict__ w_imag, const float* __restrict__ C_re,
    const float* __restrict__ C_im, const float* __restrict__ W,
    __hip_bfloat16* __restrict__ AJ_g, float* __restrict__ misc_g,
    __hip_bfloat16* __restrict__ Wb)
{
    __shared__ float2 dtA_s[NN2];
    __shared__ float2 Cn_s[NN2];
    const int tid = threadIdx.x;
    const int h = blockIdx.x;

    {   // merged conv_w: convert W row h
        float4 v = ((const float4*)(W + (size_t)h * HH))[tid];
        ushort4 o;
        o.x = bfbits(v.x); o.y = bfbits(v.y); o.z = bfbits(v.z); o.w = bfbits(v.w);
        ((ushort4*)(Wb + (size_t)h * HH))[tid] = o;
    }

    if (tid < NN2) {
        int n = tid;
        float dt = expf(log_dt[h]);
        float wr = -expf(log_w_real[n]);
        float wi = w_imag[n];
        float dar = wr * dt, dai = wi * dt;
        dtA_s[n] = make_float2(dar, dai);
        float er = expf(dar);
        float sn, cs; sincosf(dai, &sn, &cs);
        float exr = er * cs - 1.0f, exi = er * sn;
        float den = wr * wr + wi * wi;
        float fr = (exr * wr + exi * wi) / den;
        float fi = (exi * wr - exr * wi) / den;
        float cre = C_re[h * NN2 + n], cim = C_im[h * NN2 + n];
        float2 Cv = make_float2(cre * fr - cim * fi, cre * fi + cim * fr);
        Cn_s[n] = Cv;
        misc_g[h * 384 + 128 + 2 * n]     = Cv.x;
        misc_g[h * 384 + 128 + 2 * n + 1] = Cv.y;
        float magA = expf(dar * 128.0f);
        float snA, csA; sincosf(dai * 128.0f, &snA, &csA);
        misc_g[h * 384 + 192 + 2 * n]     = magA * csA;
        misc_g[h * 384 + 192 + 2 * n + 1] = magA * snA;
        misc_g[h * 384 + 256 + 2 * n]     = dar;
        misc_g[h * 384 + 256 + 2 * n + 1] = dai;
    }
    __syncthreads();

    char* ajb = (char*)AJ_g + (size_t)h * 16384;
    #pragma unroll
    for (int q = 0; q < 2; ++q) {
        int task = q * 256 + tid;              // 512 tasks: (n, j0 block of 8)
        int n = task >> 4, j0 = (task & 15) * 8;
        float2 dA = dtA_s[n];
        unsigned rw[4], iw[4];
        #pragma unroll
        for (int i2 = 0; i2 < 4; ++i2) {
            float2 a0 = cexp_n(dA, (float)(127 - j0 - 2 * i2));
            float2 a1 = cexp_n(dA, (float)(127 - j0 - 2 * i2 - 1));
            rw[i2] = (unsigned)bfbits(a0.x) | ((unsigned)bfbits(a1.x) << 16);
            iw[i2] = (unsigned)bfbits(a0.y) | ((unsigned)bfbits(a1.y) << 16);
        }
        int r0 = 2 * n, r1 = 2 * n + 1;
        *(uint4*)(ajb + SWZ(r0 * 256 + j0 * 2, r0)) = make_uint4(rw[0], rw[1], rw[2], rw[3]);
        *(uint4*)(ajb + SWZ(r1 * 256 + j0 * 2, r1)) = make_uint4(iw[0], iw[1], iw[2], iw[3]);
    }

    {   // kt[t] = 2 Re sum_n Cn a^t : 2 threads per tap
        int t = tid >> 1, nb = (tid & 1) * 16;
        float s = 0.f;
        #pragma unroll
        for (int i = 0; i < 16; ++i) {
            int n = nb + i;
            float2 a = cexp_n(dtA_s[n], (float)t);
            float2 C = Cn_s[n];
            s += C.x * a.x - C.y * a.y;
        }
        s += __shfl_xor(s, 1);
        if ((tid & 1) == 0) misc_g[h * 384 + t] = 2.0f * s;
    }
}

// ---------------- ssm LDS pool offsets (bytes), 4-batch split ----------------
#define S_U    0        // ushort U[64][128] swz (16384)
#define S_UN   16384    // 16KB union: AJ[64][128] -> AP[128][64]
#define S_P    32768    // ushort P/CS[64][64] swz (8192)
#define S_KT   40960    // kt[128]f32 | Cn f2[32] | A128 f2[32] | dtA f2[32] (1536)
#define S_KTP  42496    // ktp8: 8 copies x 264 bf16, stride 528B (4224)
#define S_TOT  46720    // 45.6 KB -> 3 blocks/CU

// ---------------------------------------------------------------------------
// Kernel 1: one block per (h, batch-half). 4 batches. AP DERIVED from AJ
// (bf16 bit ops: x2 = exp+1, negate = sign xor; bit-identical to cexp path,
// zero transcendentals). Raw y out (GELU in transpose).
// ---------------------------------------------------------------------------
__global__ __launch_bounds__(512, 6) void ssm_mfma(
    const float* __restrict__ u,
    const __hip_bfloat16* __restrict__ AJ_g,
    const float* __restrict__ misc_g,
    const float* __restrict__ Dp, __hip_bfloat16* __restrict__ g_out)
{
    extern __shared__ char smem[];
    float*  kt   = (float*)(smem + S_KT);
    float2* CnL  = (float2*)(smem + S_KT + 512);
    float2* A128 = (float2*)(smem + S_KT + 768);

    const int tid  = threadIdx.x;
    const int lane = tid & 63;
    const int wave = tid >> 6;
    const int wm   = wave >> 2;     // 0..1 : 32 bc-rows each
    const int wn   = wave & 3;      // 0..3 : col groups
    const int h    = blockIdx.x;
    const int bh   = blockIdx.y;    // batches bh*4 .. bh*4+3

    // ---- issue table staging (AJ 16KB -> S_UN, misc -> S_KT) --------------
    {
        const char* ajs = (const char*)AJ_g + (size_t)h * 16384;
        __builtin_amdgcn_global_load_lds(
            (const __attribute__((address_space(1))) void*)(ajs + tid * 16),
            (__attribute__((address_space(3))) void*)(smem + S_UN + wave * 1024), 16, 0, 0);
        __builtin_amdgcn_global_load_lds(
            (const __attribute__((address_space(1))) void*)(ajs + 8192 + tid * 16),
            (__attribute__((address_space(3))) void*)(smem + S_UN + 8192 + wave * 1024), 16, 0, 0);
        const char* ms = (const char*)misc_g + (size_t)h * 1536;
        if (tid < 64) {
            __builtin_amdgcn_global_load_lds(
                (const __attribute__((address_space(1))) void*)(ms + tid * 16),
                (__attribute__((address_space(3))) void*)(smem + S_KT), 16, 0, 0);
        }
    }

    // ---- u load (4 batches) + bf16 convert -> U LDS -----------------------
    float4 ureg[4];
    #pragma unroll
    for (int q = 0; q < 4; ++q) {
        int b = bh * 4 + q;
        ureg[q] = *(const float4*)(u + ((size_t)(b * HH + h)) * LL + tid * 4);
    }
    #pragma unroll
    for (int q = 0; q < 4; ++q) {
        int row = q * 16 + (tid >> 5);
        int j   = (tid & 31) * 4;
        ushort4 o;
        o.x = bfbits(ureg[q].x); o.y = bfbits(ureg[q].y);
        o.z = bfbits(ureg[q].z); o.w = bfbits(ureg[q].w);
        *(ushort4*)(smem + SWZ(S_U + row * 256 + j * 2, row)) = o;
    }
    asm volatile("s_waitcnt vmcnt(0)" ::: "memory");
    __syncthreads();                                         // [1] AJ/misc/U ready

    // ---- build ktp8 (shift-replicated reversed kt, bf16) -------------------
    {
        int s = wave;
        int i0 = lane * 4;
        ushort4 o;
        #pragma unroll
        for (int k = 0; k < 4; ++k) {
            int src = 127 - s - (i0 + k);
            ((unsigned short*)&o)[k] = (src >= 0) ? bfbits(kt[src]) : (unsigned short)0;
        }
        *(ushort4*)(smem + S_KTP + s * 528 + i0 * 2) = o;
        if (lane < 2) {
            *(ushort4*)(smem + S_KTP + s * 528 + 512 + lane * 8) = make_ushort4(0, 0, 0, 0);
        }
    }

    // ---- ph1: partials GEMM P[bc 64][n' 64] = U x AJ, K=128 ---------------
    f32x4 accP[2] = {};
    #pragma unroll
    for (int ks = 0; ks < 4; ++ks) {
        int kf = ks * 32 + (lane >> 4) * 8;
        bf16x8 a0, a1, b0;
        {
            int r = wm * 32 + (lane & 15);
            a0 = *(bf16x8*)(smem + SWZ(S_U + r * 256 + kf * 2, r));
            int r2 = r + 16;
            a1 = *(bf16x8*)(smem + SWZ(S_U + r2 * 256 + kf * 2, r2));
        }
        {
            int r = wn * 16 + (lane & 15);
            b0 = *(bf16x8*)(smem + SWZ(S_UN + r * 256 + kf * 2, r));
        }
        accP[0] = __builtin_amdgcn_mfma_f32_16x16x32_bf16(a0, b0, accP[0], 0, 0, 0);
        accP[1] = __builtin_amdgcn_mfma_f32_16x16x32_bf16(a1, b0, accP[1], 0, 0, 0);
    }
    #pragma unroll
    for (int mt = 0; mt < 2; ++mt)
        #pragma unroll
        for (int r = 0; r < 4; ++r) {
            int row = wm * 32 + mt * 16 + (lane >> 4) * 4 + r;
            int col = wn * 16 + (lane & 15);
            *(unsigned short*)(smem + SWZ(S_P + row * 128 + col * 2, row)) =
                bfbits(accP[mt][r]);
        }
    __syncthreads();                            // [2] AJ consumed by ph1, P stored

    // ---- AP derive from AJ: READ phase (4x ds_read_b64, no transcendentals)
    unsigned long long ajre[2], ajim[2];
    int tn[2], tj0[2];
    #pragma unroll
    for (int q = 0; q < 2; ++q) {
        int task = q * 512 + tid;               // 1024 tasks: (n, jg of 4 cols)
        int n = task >> 5, jg = task & 31;
        tn[q] = n; tj0[q] = jg * 4;
        int r0 = 2 * n, r1 = 2 * n + 1;
        ajre[q] = *(unsigned long long*)(smem + SWZ(S_UN + r0 * 256 + tj0[q] * 2, r0));
        ajim[q] = *(unsigned long long*)(smem + SWZ(S_UN + r1 * 256 + tj0[q] * 2, r1));
    }
    __syncthreads();                            // [2b] AJ reads drained

    // ---- AP write + scan + conv (all overlap) -----------------------------
    // AP[ttr][2n]=2*Re a^(ttr+1)=2*AJ[2n][126-ttr]; [2n+1]=-2*Im.
    // x2 == bf16 exponent+1 (+0x0080; values normal, |v|<=1); neg == ^0x8000.
    #pragma unroll
    for (int q = 0; q < 2; ++q) {
        int n = tn[q];
        #pragma unroll
        for (int k = 0; k < 4; ++k) {
            int j = tj0[q] + k;
            if (j < 127) {
                int ttr = 126 - j;
                unsigned short re = (unsigned short)(ajre[q] >> (16 * k));
                unsigned short im = (unsigned short)(ajim[q] >> (16 * k));
                unsigned short re2 = (unsigned short)(re + 0x0080);
                unsigned short im2 = (unsigned short)((im + 0x0080) ^ 0x8000);
                *(unsigned int*)(smem + SWZ(S_UN + ttr * 128 + n * 4, ttr)) =
                    (unsigned)re2 | ((unsigned)im2 << 16);
            }
        }
    }
    if (tid < 32) {                             // ttr = 127 (p=128) from A128
        int n = tid;
        float2 A = A128[n];
        *(unsigned int*)(smem + SWZ(S_UN + 127 * 128 + n * 4, 127)) =
            (unsigned)bfbits(2.0f * A.x) | ((unsigned)bfbits(-2.0f * A.y) << 16);
    }

    // ---- scan (tid<128: 4 batches x 32 modes), batched LDS reads -----------
    if (tid < 128) {
        int b = tid >> 5, n = tid & 31;
        float2 C = CnL[n];
        float2 A = A128[n];
        unsigned int pv[NCH];
        int offs[NCH];
        #pragma unroll
        for (int c = 0; c < NCH; ++c) {
            int row = b * 16 + c;
            offs[c] = SWZ(S_P + row * 128 + n * 4, row);
            pv[c] = *(unsigned int*)(smem + offs[c]);
        }
        float sr = 0.f, si = 0.f;
        #pragma unroll
        for (int c = 0; c < NCH; ++c) {
            float pr = f_from_bits((unsigned short)(pv[c] & 0xffff));
            float pi = f_from_bits((unsigned short)(pv[c] >> 16));
            float csr = C.x * sr - C.y * si;
            float csi = C.x * si + C.y * sr;
            *(unsigned int*)(smem + offs[c]) =
                (unsigned)bfbits(csr) | ((unsigned)bfbits(csi) << 16);
            float nsr = A.x * sr - A.y * si + pr;
            float nsi = A.x * si + A.y * sr + pi;
            sr = nsr; si = nsi;
        }
    }

    // ---- conv GEMM (full K=128, Toeplitz B from ktp8) ----------------------
    f32x4 acc[2][2] = {};
    #pragma unroll
    for (int ks = 0; ks < 4; ++ks) {
        int kf = ks * 32 + (lane >> 4) * 8;
        bf16x8 a0, a1, bv[2];
        {
            int r = wm * 32 + (lane & 15);
            a0 = *(bf16x8*)(smem + SWZ(S_U + r * 256 + kf * 2, r));
            int r2 = r + 16;
            a1 = *(bf16x8*)(smem + SWZ(S_U + r2 * 256 + kf * 2, r2));
        }
        #pragma unroll
        for (int nt = 0; nt < 2; ++nt) {
            int ttr = wn * 32 + nt * 16 + (lane & 15);
            int s   = (127 - ttr) & 7;
            int gq  = (127 - ttr + kf) >> 3;
            bv[nt] = *(bf16x8*)(smem + S_KTP + s * 528 + gq * 16);
        }
        #pragma unroll
        for (int nt = 0; nt < 2; ++nt) {
            acc[0][nt] = __builtin_amdgcn_mfma_f32_16x16x32_bf16(a0, bv[nt], acc[0][nt], 0, 0, 0);
            acc[1][nt] = __builtin_amdgcn_mfma_f32_16x16x32_bf16(a1, bv[nt], acc[1][nt], 0, 0, 0);
        }
    }
    __syncthreads();                                         // [3] CS + AP ready

    // ---- state GEMM (A = CS in S_P, B = AP in S_UN) ------------------------
    #pragma unroll
    for (int ks = 0; ks < 2; ++ks) {
        int kf = ks * 32 + (lane >> 4) * 8;
        bf16x8 a0, a1, bv[2];
        {
            int r = wm * 32 + (lane & 15);
            a0 = *(bf16x8*)(smem + SWZ(S_P + r * 128 + kf * 2, r));
            int r2 = r + 16;
            a1 = *(bf16x8*)(smem + SWZ(S_P + r2 * 128 + kf * 2, r2));
        }
        #pragma unroll
        for (int nt = 0; nt < 2; ++nt) {
            int ttr = wn * 32 + nt * 16 + (lane & 15);
            bv[nt] = *(bf16x8*)(smem + SWZ(S_UN + ttr * 128 + kf * 2, ttr));
        }
        #pragma unroll
        for (int nt = 0; nt < 2; ++nt) {
            acc[0][nt] = __builtin_amdgcn_mfma_f32_16x16x32_bf16(a0, bv[nt], acc[0][nt], 0, 0, 0);
            acc[1][nt] = __builtin_amdgcn_mfma_f32_16x16x32_bf16(a1, bv[nt], acc[1][nt], 0, 0, 0);
        }
    }

    // ---- epilogue: y = acc + D*u (no gelu) -> LDS -> packed stores --------
    const float Dv = Dp[h];
    #pragma unroll
    for (int mt = 0; mt < 2; ++mt)
        #pragma unroll
        for (int nt = 0; nt < 2; ++nt)
            #pragma unroll
            for (int r = 0; r < 4; ++r) {
                int row = wm * 32 + mt * 16 + (lane >> 4) * 4 + r;
                int ttr = wn * 32 + nt * 16 + (lane & 15);
                int off = SWZ(S_U + row * 256 + ttr * 2, row);
                float uv = f_from_bits(*(unsigned short*)(smem + off));
                float y = acc[mt][nt][r] + Dv * uv;
                *(unsigned short*)(smem + off) = bfbits(y);
            }
    __syncthreads();                                         // [4]
    #pragma unroll
    for (int q = 0; q < 2; ++q) {
        int flat = q * 512 + tid;
        int row = flat >> 4, c16 = flat & 15;
        uint4 v = *(uint4*)(smem + SWZ(S_U + row * 256 + c16 * 16, row));
        int b = bh * 4 + (row >> 4), c = row & 15;
        *(uint4*)(g_out + ((size_t)(b * HH + h)) * LL + c * CT + c16 * 8) = v;
    }
}

// ---------------------------------------------------------------------------
// Kernel 3: transpose g (B,H,L) -> gT (B,L,H), APPLYING GELU. (R20 verbatim)
// ---------------------------------------------------------------------------
__global__ __launch_bounds__(256) void transpose_g(
    const __hip_bfloat16* __restrict__ g, __hip_bfloat16* __restrict__ gT)
{
    __shared__ __hip_bfloat16 t[64][66];
    const int tid = threadIdx.x;
    const int b  = blockIdx.z;
    const int h0 = blockIdx.x * 64;
    const int l0 = blockIdx.y * 64;

    #pragma unroll
    for (int q = 0; q < 2; ++q) {
        int idx = tid + q * 256;
        int r = idx >> 3, c8 = (idx & 7) * 8;
        uint4 v = *(const uint4*)(g + ((size_t)(b * HH + h0 + r)) * LL + l0 + c8);
        unsigned int* dst = (unsigned int*)&t[r][c8];
        unsigned int* src = (unsigned int*)&v;
        #pragma unroll
        for (int w = 0; w < 4; ++w) {
            unsigned int pw = src[w];
            float a = gelu_f(f_from_bits((unsigned short)(pw & 0xffff)));
            float c = gelu_f(f_from_bits((unsigned short)(pw >> 16)));
            dst[w] = (unsigned)bfbits(a) | ((unsigned)bfbits(c) << 16);
        }
    }
    __syncthreads();
    #pragma unroll
    for (int q = 0; q < 2; ++q) {
        int idx = tid + q * 256;
        int r = idx >> 3, c8 = (idx & 7) * 8;
        unsigned short tmp[8];
        #pragma unroll
        for (int j = 0; j < 8; ++j) tmp[j] = *(unsigned short*)&t[c8 + j][r];
        uint4 o;
        o.x = (unsigned)tmp[0] | ((unsigned)tmp[1] << 16);
        o.y = (unsigned)tmp[2] | ((unsigned)tmp[3] << 16);
        o.z = (unsigned)tmp[4] | ((unsigned)tmp[5] << 16);
        o.w = (unsigned)tmp[6] | ((unsigned)tmp[7] << 16);
        *(uint4*)(gT + ((size_t)(b * LL + l0 + r)) * HH + h0 + c8) = o;
    }
}

// ---------------------------------------------------------------------------
// Kernel 4: quadrant-phased 256x256 GEMM (R20 verbatim, no setprio)
// ---------------------------------------------------------------------------
#define QSLOT 65536

#define STAGE_A_HALF(kt_, s_, h_)                                                \
    {                                                                            \
        const int k0_ = (kt_) * 64;                                              \
        _Pragma("unroll")                                                        \
        for (int v2_ = 0; v2_ < 2; ++v2_) {                                      \
            int v_ = (h_) * 2 + v2_;                                             \
            int row_ = v_ * 64 + rsub;                                           \
            const __hip_bfloat16* ga_ = Wb + (size_t)(o0 + row_) * HH + k0_ + csw; \
            char* dA_ = smem + (s_) * QSLOT + (v_ * 64 + wave * 8) * 128;        \
            __builtin_amdgcn_global_load_lds(                                    \
                (const __attribute__((address_space(1))) void*)ga_,              \
                (__attribute__((address_space(3))) void*)dA_, 16, 0, 0);         \
        }                                                                        \
    }

#define STAGE_B_HALF(kt_, s_, h_)                                                \
    {                                                                            \
        const int k0_ = (kt_) * 64;                                              \
        _Pragma("unroll")                                                        \
        for (int v2_ = 0; v2_ < 2; ++v2_) {                                      \
            int v_ = (h_) * 2 + v2_;                                             \
            int row_ = v_ * 64 + rsub;                                           \
            const __hip_bfloat16* gb_ = gT + (size_t)(n0 + row_) * HH + k0_ + csw; \
            char* dB_ = smem + (s_) * QSLOT + 32768 + (v_ * 64 + wave * 8) * 128; \
            __builtin_amdgcn_global_load_lds(                                    \
                (const __attribute__((address_space(1))) void*)gb_,              \
                (__attribute__((address_space(3))) void*)dB_, 16, 0, 0);         \
        }                                                                        \
    }

#define READ_A(af_, qa_)                                                         \
    _Pragma("unroll")                                                            \
    for (int mt = 0; mt < 2; ++mt)                                               \
        _Pragma("unroll")                                                        \
        for (int ks = 0; ks < 2; ++ks) {                                         \
            int ra = (qa_) * 128 + wm4 * 32 + mt * 16 + (lane & 15);             \
            int c  = (ks * 32 + (lane >> 4) * 8) ^ ((ra & 7) << 3);              \
            af_[mt][ks] = *(const bf16x8*)(baseA + ra * 128 + c * 2);            \
        }

#define READ_B(bf_, qb_)                                                         \
    _Pragma("unroll")                                                            \
    for (int nt = 0; nt < 4; ++nt)                                               \
        _Pragma("unroll")                                                        \
        for (int ks = 0; ks < 2; ++ks) {                                         \
            int rb = (qb_) * 128 + wn2 * 64 + nt * 16 + (lane & 15);             \
            int c  = (ks * 32 + (lane >> 4) * 8) ^ ((rb & 7) << 3);              \
            bf_[nt][ks] = *(const bf16x8*)(baseB + rb * 128 + c * 2);            \
        }

#define DO_MFMA(qa_, qb_, af_, bf_)                                              \
    _Pragma("unroll")                                                            \
    for (int mt = 0; mt < 2; ++mt)                                               \
        _Pragma("unroll")                                                        \
        for (int nt = 0; nt < 4; ++nt) {                                         \
            acc[qa_][qb_][mt][nt] = __builtin_amdgcn_mfma_f32_16x16x32_bf16(     \
                af_[mt][0], bf_[nt][0], acc[qa_][qb_][mt][nt], 0, 0, 0);         \
            acc[qa_][qb_][mt][nt] = __builtin_amdgcn_mfma_f32_16x16x32_bf16(     \
                af_[mt][1], bf_[nt][1], acc[qa_][qb_][mt][nt], 0, 0, 0);         \
        }

#define TILE_BODY(t_, s_, W0, W1, W2, DOSTAGE)                                   \
    {                                                                            \
        const char* baseA = smem + (s_) * QSLOT;                                 \
        const char* baseB = smem + (s_) * QSLOT + 32768;                         \
        bf16x8 af0[2][2], af1[2][2], bf[4][2];                                   \
        asm volatile("s_waitcnt vmcnt(" #W0 ")" ::: "memory");                   \
        __builtin_amdgcn_s_barrier();                                            \
        if (DOSTAGE) STAGE_A_HALF((t_) + 1, (s_) ^ 1, 0)                         \
        READ_A(af0, 0)                                                           \
        READ_B(bf, 0)                                                            \
        DO_MFMA(0, 0, af0, bf)                                                   \
        asm volatile("s_waitcnt vmcnt(" #W1 ")" ::: "memory");                   \
        __builtin_amdgcn_s_barrier();                                            \
        if (DOSTAGE) STAGE_B_HALF((t_) + 1, (s_) ^ 1, 0)                         \
        READ_A(af1, 1)                                                           \
        DO_MFMA(1, 0, af1, bf)                                                   \
        asm volatile("s_waitcnt vmcnt(" #W2 ")" ::: "memory");                   \
        __builtin_amdgcn_s_barrier();                                            \
        if (DOSTAGE) STAGE_A_HALF((t_) + 1, (s_) ^ 1, 1)                         \
        READ_B(bf, 1)                                                            \
        DO_MFMA(1, 1, af1, bf)                                                   \
        if (DOSTAGE) STAGE_B_HALF((t_) + 1, (s_) ^ 1, 1)                         \
        DO_MFMA(0, 1, af0, bf)                                                   \
    }

__global__ __launch_bounds__(512) void out_gemm_256p(
    const __hip_bfloat16* __restrict__ Wb,
    const __hip_bfloat16* __restrict__ gT,
    const float* __restrict__ bias,
    float* __restrict__ out)
{
    extern __shared__ char smem[];
    const int tid  = threadIdx.x;
    const int lane = tid & 63;
    const int wave = tid >> 6;
    const int wm4 = wave >> 1;
    const int wn2 = wave & 1;

    int wg  = blockIdx.x;
    int swz = (wg & 7) * 32 + (wg >> 3);
    const int o0 = (swz & 3) * 256;
    const int n0 = (swz >> 2) * 256;

    const int rsub = tid >> 3;
    const int csw  = ((tid & 7) ^ (rsub & 7)) << 3;

    f32x4 acc[2][2][2][4] = {};

    STAGE_A_HALF(0, 0, 0)
    STAGE_B_HALF(0, 0, 0)
    STAGE_A_HALF(0, 0, 1)
    STAGE_B_HALF(0, 0, 1)

    for (int t = 0; t < 15; ++t) {
        TILE_BODY(t, (t & 1), 4, 4, 4, 1)
    }
    TILE_BODY(15, 1, 4, 2, 0, 0)

    const int bb  = n0 >> 11;
    const int l0g = n0 & 2047;
    #pragma unroll
    for (int qa = 0; qa < 2; ++qa)
        #pragma unroll
        for (int mt = 0; mt < 2; ++mt)
            #pragma unroll
            for (int r = 0; r < 4; ++r) {
                int o = o0 + qa * 128 + wm4 * 32 + mt * 16 + (lane >> 4) * 4 + r;
                float bo = bias[o];
                #pragma unroll
                for (int qb = 0; qb < 2; ++qb)
                    #pragma unroll
                    for (int nt = 0; nt < 4; ++nt) {
                        int l = l0g + qb * 128 + wn2 * 64 + nt * 16 + (lane & 15);
                        out[((size_t)(bb * HH + o)) * LL + l] =
                            acc[qa][qb][mt][nt][r] + bo;
                    }
            }
}

extern "C" void kernel_launch(void* const* d_in, const int* in_sizes, int n_in,
                              void* d_out, int out_size, void* d_ws, size_t ws_size,
                              hipStream_t stream) {
    const float* u          = (const float*)d_in[0];
    const float* log_dt     = (const float*)d_in[1];
    const float* log_w_real = (const float*)d_in[2];
    const float* w_imag     = (const float*)d_in[3];
    const float* C_re       = (const float*)d_in[4];
    const float* C_im       = (const float*)d_in[5];
    const float* Dp         = (const float*)d_in[6];
    const float* W          = (const float*)d_in[7];
    const float* bias       = (const float*)d_in[8];
    float* out = (float*)d_out;

    // d_out (64 MiB) = [AJ 16MiB][misc 1.5MiB][...][g at +32MiB, 33.5MiB]
    __hip_bfloat16* AJ_g   = (__hip_bfloat16*)d_out;
    float*          misc_g = (float*)((char*)d_out + 16777216);
    __hip_bfloat16* g      = (__hip_bfloat16*)((char*)d_out + 33554432);
    // ws: gT 33.5MB | Wb 2MB
    __hip_bfloat16* gT = (__hip_bfloat16*)d_ws;
    __hip_bfloat16* Wb = (__hip_bfloat16*)((char*)d_ws + 33554432);

    hipFuncSetAttribute((const void*)ssm_mfma,
                        hipFuncAttributeMaxDynamicSharedMemorySize, S_TOT);
    hipFuncSetAttribute((const void*)out_gemm_256p,
                        hipFuncAttributeMaxDynamicSharedMemorySize, 131072);

    aux_tables<<<dim3(HH), 256, 0, stream>>>(log_dt, log_w_real, w_imag,
                                             C_re, C_im, W, AJ_g, misc_g, Wb);
    ssm_mfma<<<dim3(HH, 2), 512, S_TOT, stream>>>(u, AJ_g, misc_g, Dp, g);
    transpose_g<<<dim3(HH / 64, LL / 64, BB), 256, 0, stream>>>(g, gT);
    out_gemm_256p<<<dim3(256), 512, 131072, stream>>>(Wb, gT, bias, out);
}

// Round 22
// 93.483 us; speedup vs baseline: 1.0326x; 1.0326x over previous
//
#include <hip/hip_runtime.h>
#include <hip/hip_bf16.h>

#define HH 1024
#define LL 2048
#define BB 8
#define NN2 32     // complex modes
#define CT 128     // chunk size
#define NCH 16     // LL / CT

typedef short bf16x8 __attribute__((ext_vector_type(8)));
typedef float f32x4  __attribute__((ext_vector_type(4)));

static __device__ __forceinline__ unsigned short bfbits(float x) {
    __hip_bfloat16 h = __float2bfloat16(x);
    return *(unsigned short*)&h;
}
static __device__ __forceinline__ float f_from_bits(unsigned short b) {
    __hip_bfloat16 h; *(unsigned short*)&h = b; return __bfloat162float(h);
}
// exp(dA * p), native ops, explicit range reduction.
static __device__ __forceinline__ float2 cexp_n(float2 dA, float p) {
    float mag = __expf(dA.x * p);
    float rev = dA.y * p * 0.15915494309f;
    rev -= floorf(rev);
    float ang = rev * 6.28318530718f;
    return make_float2(mag * __cosf(ang), mag * __sinf(ang));
}
static __device__ __forceinline__ float gelu_f(float y) {
    float z = 0.7978845608f * (y + 0.044715f * y * y * y);
    float e = __expf(2.0f * z);
    return 0.5f * y * (1.0f + (1.0f - 2.0f / (e + 1.0f)));
}

#define SWZ(off, row) ((off) ^ (((row) & 7) << 4))

// ---------------------------------------------------------------------------
// Kernel 0: per-h tables -> global, PRE-SWIZZLED.
// misc = 384 floats: kt[128] | Cn[64] | A128[64] | dtA[64] | pad[64]
// ---------------------------------------------------------------------------
__global__ __launch_bounds__(256) void aux_tables(
    const float* __restrict__ log_dt, const float* __restrict__ log_w_real,
    const float* __restrict__ w_imag, const float* __restrict__ C_re,
    const float* __restrict__ C_im, const float* __restrict__ W,
    __hip_bfloat16* __restrict__ AJ_g, float* __restrict__ misc_g,
    __hip_bfloat16* __restrict__ Wb)
{
    __shared__ float2 dtA_s[NN2];
    __shared__ float2 Cn_s[NN2];
    const int tid = threadIdx.x;
    const int h = blockIdx.x;

    {   // merged conv_w: convert W row h
        float4 v = ((const float4*)(W + (size_t)h * HH))[tid];
        ushort4 o;
        o.x = bfbits(v.x); o.y = bfbits(v.y); o.z = bfbits(v.z); o.w = bfbits(v.w);
        ((ushort4*)(Wb + (size_t)h * HH))[tid] = o;
    }

    if (tid < NN2) {
        int n = tid;
        float dt = expf(log_dt[h]);
        float wr = -expf(log_w_real[n]);
        float wi = w_imag[n];
        float dar = wr * dt, dai = wi * dt;
        dtA_s[n] = make_float2(dar, dai);
        float er = expf(dar);
        float sn, cs; sincosf(dai, &sn, &cs);
        float exr = er * cs - 1.0f, exi = er * sn;
        float den = wr * wr + wi * wi;
        float fr = (exr * wr + exi * wi) / den;
        float fi = (exi * wr - exr * wi) / den;
        float cre = C_re[h * NN2 + n], cim = C_im[h * NN2 + n];
        float2 Cv = make_float2(cre * fr - cim * fi, cre * fi + cim * fr);
        Cn_s[n] = Cv;
        misc_g[h * 384 + 128 + 2 * n]     = Cv.x;
        misc_g[h * 384 + 128 + 2 * n + 1] = Cv.y;
        float magA = expf(dar * 128.0f);
        float snA, csA; sincosf(dai * 128.0f, &snA, &csA);
        misc_g[h * 384 + 192 + 2 * n]     = magA * csA;
        misc_g[h * 384 + 192 + 2 * n + 1] = magA * snA;
        misc_g[h * 384 + 256 + 2 * n]     = dar;
        misc_g[h * 384 + 256 + 2 * n + 1] = dai;
    }
    __syncthreads();

    char* ajb = (char*)AJ_g + (size_t)h * 16384;
    #pragma unroll
    for (int q = 0; q < 2; ++q) {
        int task = q * 256 + tid;              // 512 tasks: (n, j0 block of 8)
        int n = task >> 4, j0 = (task & 15) * 8;
        float2 dA = dtA_s[n];
        unsigned rw[4], iw[4];
        #pragma unroll
        for (int i2 = 0; i2 < 4; ++i2) {
            float2 a0 = cexp_n(dA, (float)(127 - j0 - 2 * i2));
            float2 a1 = cexp_n(dA, (float)(127 - j0 - 2 * i2 - 1));
            rw[i2] = (unsigned)bfbits(a0.x) | ((unsigned)bfbits(a1.x) << 16);
            iw[i2] = (unsigned)bfbits(a0.y) | ((unsigned)bfbits(a1.y) << 16);
        }
        int r0 = 2 * n, r1 = 2 * n + 1;
        *(uint4*)(ajb + SWZ(r0 * 256 + j0 * 2, r0)) = make_uint4(rw[0], rw[1], rw[2], rw[3]);
        *(uint4*)(ajb + SWZ(r1 * 256 + j0 * 2, r1)) = make_uint4(iw[0], iw[1], iw[2], iw[3]);
    }

    {   // kt[t] = 2 Re sum_n Cn a^t : 2 threads per tap
        int t = tid >> 1, nb = (tid & 1) * 16;
        float s = 0.f;
        #pragma unroll
        for (int i = 0; i < 16; ++i) {
            int n = nb + i;
            float2 a = cexp_n(dtA_s[n], (float)t);
            float2 C = Cn_s[n];
            s += C.x * a.x - C.y * a.y;
        }
        s += __shfl_xor(s, 1);
        if ((tid & 1) == 0) misc_g[h * 384 + t] = 2.0f * s;
    }
}

// ---------------- ssm LDS pool offsets (bytes), 4-batch split ----------------
#define S_U    0        // ushort U[64][128] swz (16384)
#define S_UN   16384    // 16KB union: AJ[64][128] -> AP[128][64]
#define S_P    32768    // ushort P/CS[64][64] swz (8192)
#define S_KT   40960    // kt[128]f32 | Cn f2[32] | A128 f2[32] | dtA f2[32] (1536)
#define S_KTP  42496    // ktp8: 8 copies x 264 bf16, stride 528B (4224)
#define S_TOT  46720    // 45.6 KB -> 3 blocks/CU

// ---------------------------------------------------------------------------
// Kernel 1: one block per (h, batch-half). 4 batches. AP built IN-KERNEL
// (cexp path). Raw y out (GELU in transpose).
// ---------------------------------------------------------------------------
__global__ __launch_bounds__(512, 6) void ssm_mfma(
    const float* __restrict__ u,
    const __hip_bfloat16* __restrict__ AJ_g,
    const float* __restrict__ misc_g,
    const float* __restrict__ Dp, __hip_bfloat16* __restrict__ g_out)
{
    extern __shared__ char smem[];
    float*  kt   = (float*)(smem + S_KT);
    float2* CnL  = (float2*)(smem + S_KT + 512);
    float2* A128 = (float2*)(smem + S_KT + 768);
    float2* dtAL = (float2*)(smem + S_KT + 1024);

    const int tid  = threadIdx.x;
    const int lane = tid & 63;
    const int wave = tid >> 6;
    const int wm   = wave >> 2;     // 0..1 : 32 bc-rows each
    const int wn   = wave & 3;      // 0..3 : col groups
    const int h    = blockIdx.x;
    const int bh   = blockIdx.y;    // batches bh*4 .. bh*4+3

    // ---- issue table staging (AJ 16KB -> S_UN, misc 1.5KB -> S_KT) --------
    {
        const char* ajs = (const char*)AJ_g + (size_t)h * 16384;
        __builtin_amdgcn_global_load_lds(
            (const __attribute__((address_space(1))) void*)(ajs + tid * 16),
            (__attribute__((address_space(3))) void*)(smem + S_UN + wave * 1024), 16, 0, 0);
        __builtin_amdgcn_global_load_lds(
            (const __attribute__((address_space(1))) void*)(ajs + 8192 + tid * 16),
            (__attribute__((address_space(3))) void*)(smem + S_UN + 8192 + wave * 1024), 16, 0, 0);
        const char* ms = (const char*)misc_g + (size_t)h * 1536;
        if (tid < 64) {
            __builtin_amdgcn_global_load_lds(
                (const __attribute__((address_space(1))) void*)(ms + tid * 16),
                (__attribute__((address_space(3))) void*)(smem + S_KT), 16, 0, 0);
        } else if (tid < 96) {
            __builtin_amdgcn_global_load_lds(
                (const __attribute__((address_space(1))) void*)(ms + tid * 16),
                (__attribute__((address_space(3))) void*)(smem + S_KT + 1024), 16, 0, 0);
        }
    }

    // ---- u load (4 batches) + bf16 convert -> U LDS -----------------------
    float4 ureg[4];
    #pragma unroll
    for (int q = 0; q < 4; ++q) {
        int b = bh * 4 + q;
        ureg[q] = *(const float4*)(u + ((size_t)(b * HH + h)) * LL + tid * 4);
    }
    #pragma unroll
    for (int q = 0; q < 4; ++q) {
        int row = q * 16 + (tid >> 5);
        int j   = (tid & 31) * 4;
        ushort4 o;
        o.x = bfbits(ureg[q].x); o.y = bfbits(ureg[q].y);
        o.z = bfbits(ureg[q].z); o.w = bfbits(ureg[q].w);
        *(ushort4*)(smem + SWZ(S_U + row * 256 + j * 2, row)) = o;
    }
    asm volatile("s_waitcnt vmcnt(0)" ::: "memory");
    __syncthreads();                                         // [1] AJ/misc/U ready

    // ---- build ktp8 (shift-replicated reversed kt, bf16) -------------------
    {
        int s = wave;
        int i0 = lane * 4;
        ushort4 o;
        #pragma unroll
        for (int k = 0; k < 4; ++k) {
            int src = 127 - s - (i0 + k);
            ((unsigned short*)&o)[k] = (src >= 0) ? bfbits(kt[src]) : (unsigned short)0;
        }
        *(ushort4*)(smem + S_KTP + s * 528 + i0 * 2) = o;
        if (lane < 2) {
            *(ushort4*)(smem + S_KTP + s * 528 + 512 + lane * 8) = make_ushort4(0, 0, 0, 0);
        }
    }

    // ---- ph1: partials GEMM P[bc 64][n' 64] = U x AJ, K=128 ---------------
    f32x4 accP[2] = {};
    #pragma unroll
    for (int ks = 0; ks < 4; ++ks) {
        int kf = ks * 32 + (lane >> 4) * 8;
        bf16x8 a0, a1, b0;
        {
            int r = wm * 32 + (lane & 15);
            a0 = *(bf16x8*)(smem + SWZ(S_U + r * 256 + kf * 2, r));
            int r2 = r + 16;
            a1 = *(bf16x8*)(smem + SWZ(S_U + r2 * 256 + kf * 2, r2));
        }
        {
            int r = wn * 16 + (lane & 15);
            b0 = *(bf16x8*)(smem + SWZ(S_UN + r * 256 + kf * 2, r));
        }
        accP[0] = __builtin_amdgcn_mfma_f32_16x16x32_bf16(a0, b0, accP[0], 0, 0, 0);
        accP[1] = __builtin_amdgcn_mfma_f32_16x16x32_bf16(a1, b0, accP[1], 0, 0, 0);
    }
    #pragma unroll
    for (int mt = 0; mt < 2; ++mt)
        #pragma unroll
        for (int r = 0; r < 4; ++r) {
            int row = wm * 32 + mt * 16 + (lane >> 4) * 4 + r;
            int col = wn * 16 + (lane & 15);
            *(unsigned short*)(smem + SWZ(S_P + row * 128 + col * 2, row)) =
                bfbits(accP[mt][r]);
        }
    __syncthreads();                            // [2] AJ consumed, P stored

    // ---- AP build IN-KERNEL into freed S_UN (overlaps scan + conv) --------
    #pragma unroll
    for (int q = 0; q < 8; ++q) {
        int idx = q * 512 + tid;                // 4096 (n,ttr) tasks
        int n = idx >> 7, ttr = idx & 127;
        float2 a = cexp_n(dtAL[n], (float)(ttr + 1));
        int off = SWZ(S_UN + ttr * 128 + n * 4, ttr);
        *(unsigned int*)(smem + off) =
            (unsigned)bfbits(2.0f * a.x) | ((unsigned)bfbits(-2.0f * a.y) << 16);
    }

    // ---- scan (tid<128: 4 batches x 32 modes), batched LDS reads -----------
    if (tid < 128) {
        int b = tid >> 5, n = tid & 31;
        float2 C = CnL[n];
        float2 A = A128[n];
        unsigned int pv[NCH];
        int offs[NCH];
        #pragma unroll
        for (int c = 0; c < NCH; ++c) {
            int row = b * 16 + c;
            offs[c] = SWZ(S_P + row * 128 + n * 4, row);
            pv[c] = *(unsigned int*)(smem + offs[c]);
        }
        float sr = 0.f, si = 0.f;
        #pragma unroll
        for (int c = 0; c < NCH; ++c) {
            float pr = f_from_bits((unsigned short)(pv[c] & 0xffff));
            float pi = f_from_bits((unsigned short)(pv[c] >> 16));
            float csr = C.x * sr - C.y * si;
            float csi = C.x * si + C.y * sr;
            *(unsigned int*)(smem + offs[c]) =
                (unsigned)bfbits(csr) | ((unsigned)bfbits(csi) << 16);
            float nsr = A.x * sr - A.y * si + pr;
            float nsi = A.x * si + A.y * sr + pi;
            sr = nsr; si = nsi;
        }
    }

    // ---- conv GEMM (full K=128, Toeplitz B from ktp8) ----------------------
    f32x4 acc[2][2] = {};
    #pragma unroll
    for (int ks = 0; ks < 4; ++ks) {
        int kf = ks * 32 + (lane >> 4) * 8;
        bf16x8 a0, a1, bv[2];
        {
            int r = wm * 32 + (lane & 15);
            a0 = *(bf16x8*)(smem + SWZ(S_U + r * 256 + kf * 2, r));
            int r2 = r + 16;
            a1 = *(bf16x8*)(smem + SWZ(S_U + r2 * 256 + kf * 2, r2));
        }
        #pragma unroll
        for (int nt = 0; nt < 2; ++nt) {
            int ttr = wn * 32 + nt * 16 + (lane & 15);
            int s   = (127 - ttr) & 7;
            int gq  = (127 - ttr + kf) >> 3;
            bv[nt] = *(bf16x8*)(smem + S_KTP + s * 528 + gq * 16);
        }
        #pragma unroll
        for (int nt = 0; nt < 2; ++nt) {
            acc[0][nt] = __builtin_amdgcn_mfma_f32_16x16x32_bf16(a0, bv[nt], acc[0][nt], 0, 0, 0);
            acc[1][nt] = __builtin_amdgcn_mfma_f32_16x16x32_bf16(a1, bv[nt], acc[1][nt], 0, 0, 0);
        }
    }
    __syncthreads();                                         // [3] CS + AP ready

    // ---- state GEMM (A = CS in S_P, B = AP in S_UN) ------------------------
    #pragma unroll
    for (int ks = 0; ks < 2; ++ks) {
        int kf = ks * 32 + (lane >> 4) * 8;
        bf16x8 a0, a1, bv[2];
        {
            int r = wm * 32 + (lane & 15);
            a0 = *(bf16x8*)(smem + SWZ(S_P + r * 128 + kf * 2, r));
            int r2 = r + 16;
            a1 = *(bf16x8*)(smem + SWZ(S_P + r2 * 128 + kf * 2, r2));
        }
        #pragma unroll
        for (int nt = 0; nt < 2; ++nt) {
            int ttr = wn * 32 + nt * 16 + (lane & 15);
            bv[nt] = *(bf16x8*)(smem + SWZ(S_UN + ttr * 128 + kf * 2, ttr));
        }
        #pragma unroll
        for (int nt = 0; nt < 2; ++nt) {
            acc[0][nt] = __builtin_amdgcn_mfma_f32_16x16x32_bf16(a0, bv[nt], acc[0][nt], 0, 0, 0);
            acc[1][nt] = __builtin_amdgcn_mfma_f32_16x16x32_bf16(a1, bv[nt], acc[1][nt], 0, 0, 0);
        }
    }

    // ---- epilogue: y = acc + D*u (no gelu) -> LDS -> packed stores --------
    const float Dv = Dp[h];
    #pragma unroll
    for (int mt = 0; mt < 2; ++mt)
        #pragma unroll
        for (int nt = 0; nt < 2; ++nt)
            #pragma unroll
            for (int r = 0; r < 4; ++r) {
                int row = wm * 32 + mt * 16 + (lane >> 4) * 4 + r;
                int ttr = wn * 32 + nt * 16 + (lane & 15);
                int off = SWZ(S_U + row * 256 + ttr * 2, row);
                float uv = f_from_bits(*(unsigned short*)(smem + off));
                float y = acc[mt][nt][r] + Dv * uv;
                *(unsigned short*)(smem + off) = bfbits(y);
            }
    __syncthreads();                                         // [4]
    #pragma unroll
    for (int q = 0; q < 2; ++q) {
        int flat = q * 512 + tid;
        int row = flat >> 4, c16 = flat & 15;
        uint4 v = *(uint4*)(smem + SWZ(S_U + row * 256 + c16 * 16, row));
        int b = bh * 4 + (row >> 4), c = row & 15;
        *(uint4*)(g_out + ((size_t)(b * HH + h)) * LL + c * CT + c16 * 8) = v;
    }
}

// ---------------------------------------------------------------------------
// Kernel 3: transpose g (B,H,L) -> gT (B,L,H), APPLYING GELU.
// ---------------------------------------------------------------------------
__global__ __launch_bounds__(256) void transpose_g(
    const __hip_bfloat16* __restrict__ g, __hip_bfloat16* __restrict__ gT)
{
    __shared__ __hip_bfloat16 t[64][66];
    const int tid = threadIdx.x;
    const int b  = blockIdx.z;
    const int h0 = blockIdx.x * 64;
    const int l0 = blockIdx.y * 64;

    #pragma unroll
    for (int q = 0; q < 2; ++q) {
        int idx = tid + q * 256;
        int r = idx >> 3, c8 = (idx & 7) * 8;
        uint4 v = *(const uint4*)(g + ((size_t)(b * HH + h0 + r)) * LL + l0 + c8);
        unsigned int* dst = (unsigned int*)&t[r][c8];
        unsigned int* src = (unsigned int*)&v;
        #pragma unroll
        for (int w = 0; w < 4; ++w) {
            unsigned int pw = src[w];
            float a = gelu_f(f_from_bits((unsigned short)(pw & 0xffff)));
            float c = gelu_f(f_from_bits((unsigned short)(pw >> 16)));
            dst[w] = (unsigned)bfbits(a) | ((unsigned)bfbits(c) << 16);
        }
    }
    __syncthreads();
    #pragma unroll
    for (int q = 0; q < 2; ++q) {
        int idx = tid + q * 256;
        int r = idx >> 3, c8 = (idx & 7) * 8;
        unsigned short tmp[8];
        #pragma unroll
        for (int j = 0; j < 8; ++j) tmp[j] = *(unsigned short*)&t[c8 + j][r];
        uint4 o;
        o.x = (unsigned)tmp[0] | ((unsigned)tmp[1] << 16);
        o.y = (unsigned)tmp[2] | ((unsigned)tmp[3] << 16);
        o.z = (unsigned)tmp[4] | ((unsigned)tmp[5] << 16);
        o.w = (unsigned)tmp[6] | ((unsigned)tmp[7] << 16);
        *(uint4*)(gT + ((size_t)(b * LL + l0 + r)) * HH + h0 + c8) = o;
    }
}

// ---------------------------------------------------------------------------
// Kernel 4: quadrant-phased 256x256 GEMM (counted vmcnt(4), no setprio)
// ---------------------------------------------------------------------------
#define QSLOT 65536

#define STAGE_A_HALF(kt_, s_, h_)                                                \
    {                                                                            \
        const int k0_ = (kt_) * 64;                                              \
        _Pragma("unroll")                                                        \
        for (int v2_ = 0; v2_ < 2; ++v2_) {                                      \
            int v_ = (h_) * 2 + v2_;                                             \
            int row_ = v_ * 64 + rsub;                                           \
            const __hip_bfloat16* ga_ = Wb + (size_t)(o0 + row_) * HH + k0_ + csw; \
            char* dA_ = smem + (s_) * QSLOT + (v_ * 64 + wave * 8) * 128;        \
            __builtin_amdgcn_global_load_lds(                                    \
                (const __attribute__((address_space(1))) void*)ga_,              \
                (__attribute__((address_space(3))) void*)dA_, 16, 0, 0);         \
        }                                                                        \
    }

#define STAGE_B_HALF(kt_, s_, h_)                                                \
    {                                                                            \
        const int k0_ = (kt_) * 64;                                              \
        _Pragma("unroll")                                                        \
        for (int v2_ = 0; v2_ < 2; ++v2_) {                                      \
            int v_ = (h_) * 2 + v2_;                                             \
            int row_ = v_ * 64 + rsub;                                           \
            const __hip_bfloat16* gb_ = gT + (size_t)(n0 + row_) * HH + k0_ + csw; \
            char* dB_ = smem + (s_) * QSLOT + 32768 + (v_ * 64 + wave * 8) * 128; \
            __builtin_amdgcn_global_load_lds(                                    \
                (const __attribute__((address_space(1))) void*)gb_,              \
                (__attribute__((address_space(3))) void*)dB_, 16, 0, 0);         \
        }                                                                        \
    }

#define READ_A(af_, qa_)                                                         \
    _Pragma("unroll")                                                            \
    for (int mt = 0; mt < 2; ++mt)                                               \
        _Pragma("unroll")                                                        \
        for (int ks = 0; ks < 2; ++ks) {                                         \
            int ra = (qa_) * 128 + wm4 * 32 + mt * 16 + (lane & 15);             \
            int c  = (ks * 32 + (lane >> 4) * 8) ^ ((ra & 7) << 3);              \
            af_[mt][ks] = *(const bf16x8*)(baseA + ra * 128 + c * 2);            \
        }

#define READ_B(bf_, qb_)                                                         \
    _Pragma("unroll")                                                            \
    for (int nt = 0; nt < 4; ++nt)                                               \
        _Pragma("unroll")                                                        \
        for (int ks = 0; ks < 2; ++ks) {                                         \
            int rb = (qb_) * 128 + wn2 * 64 + nt * 16 + (lane & 15);             \
            int c  = (ks * 32 + (lane >> 4) * 8) ^ ((rb & 7) << 3);              \
            bf_[nt][ks] = *(const bf16x8*)(baseB + rb * 128 + c * 2);            \
        }

#define DO_MFMA(qa_, qb_, af_, bf_)                                              \
    _Pragma("unroll")                                                            \
    for (int mt = 0; mt < 2; ++mt)                                               \
        _Pragma("unroll")                                                        \
        for (int nt = 0; nt < 4; ++nt) {                                         \
            acc[qa_][qb_][mt][nt] = __builtin_amdgcn_mfma_f32_16x16x32_bf16(     \
                af_[mt][0], bf_[nt][0], acc[qa_][qb_][mt][nt], 0, 0, 0);         \
            acc[qa_][qb_][mt][nt] = __builtin_amdgcn_mfma_f32_16x16x32_bf16(     \
                af_[mt][1], bf_[nt][1], acc[qa_][qb_][mt][nt], 0, 0, 0);         \
        }

#define TILE_BODY(t_, s_, W0, W1, W2, DOSTAGE)                                   \
    {                                                                            \
        const char* baseA = smem + (s_) * QSLOT;                                 \
        const char* baseB = smem + (s_) * QSLOT + 32768;                         \
        bf16x8 af0[2][2], af1[2][2], bf[4][2];                                   \
        asm volatile("s_waitcnt vmcnt(" #W0 ")" ::: "memory");                   \
        __builtin_amdgcn_s_barrier();                                            \
        if (DOSTAGE) STAGE_A_HALF((t_) + 1, (s_) ^ 1, 0)                         \
        READ_A(af0, 0)                                                           \
        READ_B(bf, 0)                                                            \
        DO_MFMA(0, 0, af0, bf)                                                   \
        asm volatile("s_waitcnt vmcnt(" #W1 ")" ::: "memory");                   \
        __builtin_amdgcn_s_barrier();                                            \
        if (DOSTAGE) STAGE_B_HALF((t_) + 1, (s_) ^ 1, 0)                         \
        READ_A(af1, 1)                                                           \
        DO_MFMA(1, 0, af1, bf)                                                   \
        asm volatile("s_waitcnt vmcnt(" #W2 ")" ::: "memory");                   \
        __builtin_amdgcn_s_barrier();                                            \
        if (DOSTAGE) STAGE_A_HALF((t_) + 1, (s_) ^ 1, 1)                         \
        READ_B(bf, 1)                                                            \
        DO_MFMA(1, 1, af1, bf)                                                   \
        if (DOSTAGE) STAGE_B_HALF((t_) + 1, (s_) ^ 1, 1)                         \
        DO_MFMA(0, 1, af0, bf)                                                   \
    }

__global__ __launch_bounds__(512) void out_gemm_256p(
    const __hip_bfloat16* __restrict__ Wb,
    const __hip_bfloat16* __restrict__ gT,
    const float* __restrict__ bias,
    float* __restrict__ out)
{
    extern __shared__ char smem[];
    const int tid  = threadIdx.x;
    const int lane = tid & 63;
    const int wave = tid >> 6;
    const int wm4 = wave >> 1;
    const int wn2 = wave & 1;

    int wg  = blockIdx.x;
    int swz = (wg & 7) * 32 + (wg >> 3);
    const int o0 = (swz & 3) * 256;
    const int n0 = (swz >> 2) * 256;

    const int rsub = tid >> 3;
    const int csw  = ((tid & 7) ^ (rsub & 7)) << 3;

    f32x4 acc[2][2][2][4] = {};

    STAGE_A_HALF(0, 0, 0)
    STAGE_B_HALF(0, 0, 0)
    STAGE_A_HALF(0, 0, 1)
    STAGE_B_HALF(0, 0, 1)

    for (int t = 0; t < 15; ++t) {
        TILE_BODY(t, (t & 1), 4, 4, 4, 1)
    }
    TILE_BODY(15, 1, 4, 2, 0, 0)

    const int bb  = n0 >> 11;
    const int l0g = n0 & 2047;
    #pragma unroll
    for (int qa = 0; qa < 2; ++qa)
        #pragma unroll
        for (int mt = 0; mt < 2; ++mt)
            #pragma unroll
            for (int r = 0; r < 4; ++r) {
                int o = o0 + qa * 128 + wm4 * 32 + mt * 16 + (lane >> 4) * 4 + r;
                float bo = bias[o];
                #pragma unroll
                for (int qb = 0; qb < 2; ++qb)
                    #pragma unroll
                    for (int nt = 0; nt < 4; ++nt) {
                        int l = l0g + qb * 128 + wn2 * 64 + nt * 16 + (lane & 15);
                        out[((size_t)(bb * HH + o)) * LL + l] =
                            acc[qa][qb][mt][nt][r] + bo;
                    }
            }
}

extern "C" void kernel_launch(void* const* d_in, const int* in_sizes, int n_in,
                              void* d_out, int out_size, void* d_ws, size_t ws_size,
                              hipStream_t stream) {
    const float* u          = (const float*)d_in[0];
    const float* log_dt     = (const float*)d_in[1];
    const float* log_w_real = (const float*)d_in[2];
    const float* w_imag     = (const float*)d_in[3];
    const float* C_re       = (const float*)d_in[4];
    const float* C_im       = (const float*)d_in[5];
    const float* Dp         = (const float*)d_in[6];
    const float* W          = (const float*)d_in[7];
    const float* bias       = (const float*)d_in[8];
    float* out = (float*)d_out;

    // d_out (64 MiB) = [AJ 16MiB][misc 1.5MiB][...][g at +32MiB, 33.5MiB]
    __hip_bfloat16* AJ_g   = (__hip_bfloat16*)d_out;
    float*          misc_g = (float*)((char*)d_out + 16777216);
    __hip_bfloat16* g      = (__hip_bfloat16*)((char*)d_out + 33554432);
    // ws: gT 33.5MB | Wb 2MB
    __hip_bfloat16* gT = (__hip_bfloat16*)d_ws;
    __hip_bfloat16* Wb = (__hip_bfloat16*)((char*)d_ws + 33554432);

    hipFuncSetAttribute((const void*)ssm_mfma,
                        hipFuncAttributeMaxDynamicSharedMemorySize, S_TOT);
    hipFuncSetAttribute((const void*)out_gemm_256p,
                        hipFuncAttributeMaxDynamicSharedMemorySize, 131072);

    aux_tables<<<dim3(HH), 256, 0, stream>>>(log_dt, log_w_real, w_imag,
                                             C_re, C_im, W, AJ_g, misc_g, Wb);
    ssm_mfma<<<dim3(HH, 2), 512, S_TOT, stream>>>(u, AJ_g, misc_g, Dp, g);
    transpose_g<<<dim3(HH / 64, LL / 64, BB), 256, 0, stream>>>(g, gT);
    out_gemm_256p<<<dim3(256), 512, 131072, stream>>>(Wb, gT, bias, out);
}